// Round 5
// baseline (230.981 us; speedup 1.0000x reference)
//
#include <hip/hip_runtime.h>

#define NPIX (512 * 512)  // 262144
#define NB 32
#define NK 4
#define TPB 256
#define CPB 64                      // chunks per (b,k)
#define CHUNK (NPIX / CPB)          // 4096 elems
#define T4PT (CHUNK / (TPB * 4))    // 4 float4 per thread per input

// ws layout (floats):
// [0..127]   focal_sum  (b*4+k)
// [128..255] p_sum
// [256..383] inter
// [384..511] m_sum
// [512..639] mi
// [640..671] t_sum (per b)
#define WS_FLOATS 672

__global__ __launch_bounds__(TPB, 8) void sam_loss_pass1(
    const float* __restrict__ x, const float* __restrict__ t,
    float* __restrict__ ws) {
  // XCD-aware swizzle: the 4 k-siblings of one (b,c) chunk differ by 8 in
  // blockIdx -> same XCD (round-robin %8) -> t-chunk reused from that L2.
  const int blk = blockIdx.x;            // (bc>>3)*32 + k*8 + (bc&7)
  const int low = blk & 7;
  const int k = (blk >> 3) & 3;
  const int bc = ((blk >> 5) << 3) | low;
  const int b = bc >> 6;                 // bc / CPB
  const int c = bc & (CPB - 1);          // bc % CPB

  const float4* __restrict__ t4 =
      (const float4*)(t + (size_t)b * NPIX + (size_t)c * CHUNK);
  const float4* __restrict__ x4 =
      (const float4*)(x + ((size_t)b * NK + k) * NPIX + (size_t)c * CHUNK);

  // issue all 8 loads up front (8 KB/wave in flight)
  float4 xv[T4PT], tv[T4PT];
#pragma unroll
  for (int it = 0; it < T4PT; ++it) {
    const int i = it * TPB + threadIdx.x;
    xv[it] = x4[i];
    tv[it] = t4[i];
  }

  float fs = 0.f, ps = 0.f, is_ = 0.f;
  // integer counts live on the scalar pipe (wave-uniform after ballot)
  unsigned int msc = 0u, misc = 0u, tsc = 0u;

#pragma unroll
  for (int it = 0; it < T4PT; ++it) {
    const float xx[4] = {xv[it].x, xv[it].y, xv[it].z, xv[it].w};
    const float tt[4] = {tv[it].x, tv[it].y, tv[it].z, tv[it].w};
#pragma unroll
    for (int j = 0; j < 4; ++j) {
      const float xf = xx[j];
      const float tf = tt[j];  // exactly 0.0 or 1.0
      const bool tpos = tf != 0.0f;
      const bool pos = xf >= 0.0f;
      const unsigned long long tb = __ballot(tpos);
      const unsigned long long pb = __ballot(pos);
      tsc += (unsigned)__popcll(tb);        // scalar pipe
      msc += (unsigned)__popcll(pb);        // scalar pipe
      misc += (unsigned)__popcll(pb & tb);  // scalar pipe

      const float ax = fabsf(xf);
      const float e = __expf(-ax);                       // exp(-|x|) in (0,1]
      const float r = __builtin_amdgcn_rcpf(1.0f + e);   // sigmoid(|x|)
      const float er = e * r;                            // sigmoid(-|x|)
      const bool mx = pos != tpos;
      const float pc = mx ? er : r;   // prob. of correct class in (0,1)
      const float bce = -__logf(pc);  // = t?softplus(-x):softplus(x)
      const float sp = pos ? r : er;  // sigmoid(x)
      const float om = tf - sp;       // |om| = 1 - exp(-bce)
      fs = fmaf(om * om, bce, fs);
      ps += sp;
      is_ = fmaf(sp, tf, is_);
    }
  }

  // thread -> wave -> block -> global reduction
  __shared__ float red[TPB / 64][6];
  const int lane = threadIdx.x & 63;
  const int wid = threadIdx.x >> 6;
  float vals[3] = {fs, ps, is_};
#pragma unroll
  for (int j = 0; j < 3; ++j) {
    float v = vals[j];
#pragma unroll
    for (int off = 32; off > 0; off >>= 1) v += __shfl_down(v, off, 64);
    if (lane == 0) red[wid][j] = v;
  }
  if (lane == 0) {
    red[wid][3] = (float)msc;   // already wave-total
    red[wid][4] = (float)misc;
    red[wid][5] = (float)tsc;
  }
  __syncthreads();
  if (threadIdx.x < 6) {
    const int j = threadIdx.x;
    const float v = red[0][j] + red[1][j] + red[2][j] + red[3][j];
    if (j < 5) {
      atomicAdd(ws + j * (NB * NK) + b * NK + k, v);
    } else if (k == 0) {
      atomicAdd(ws + 5 * (NB * NK) + b, v);
    }
  }
}

__global__ __launch_bounds__(64) void sam_loss_pass2(
    const float* __restrict__ ws, const float* __restrict__ ious,
    float* __restrict__ out) {
  const float AREA_LO[4] = {0.04f, 0.0f, 0.01f, 0.16f};
  const float AREA_HI[4] = {0.64f, 0.04f, 0.25f, 1.0f};
  const float S = 1e-4f;
  const int lane = threadIdx.x;

  float pf = 0.f, pd = 0.f, pi = 0.f, sv = 0.f;
  if (lane < NB) {
    const int b = lane;
    const float tsum = ws[5 * (NB * NK) + b];
    const float ratio = tsum / (float)NPIX;
    float cnt = 0.f, sf = 0.f, sd = 0.f, si = 0.f;
#pragma unroll
    for (int k = 0; k < NK; ++k) {
      const bool valid = (ratio > AREA_LO[k]) && (ratio < AREA_HI[k]);
      if (valid) {
        const int idx = b * NK + k;
        const float focal = 0.8f * ws[idx] / (float)NPIX;
        const float psum = ws[1 * (NB * NK) + idx];
        const float inter = ws[2 * (NB * NK) + idx];
        const float msum = ws[3 * (NB * NK) + idx];
        const float mi = ws[4 * (NB * NK) + idx];
        const float dice = 1.0f - (2.0f * inter + S) / (psum + tsum + S);
        const float iou_gt = (mi + S) / (msum + tsum - mi + S);
        const float d = ious[idx] - iou_gt;
        cnt += 1.0f;
        sf += focal;
        sd += dice;
        si += d * d;
      }
    }
    if (cnt > 0.f) {
      pf = sf / cnt;
      pd = sd / cnt;
      pi = si / cnt;
      sv = 1.0f;
    }
  }
#pragma unroll
  for (int off = 32; off > 0; off >>= 1) {
    pf += __shfl_down(pf, off, 64);
    pd += __shfl_down(pd, off, 64);
    pi += __shfl_down(pi, off, 64);
    sv += __shfl_down(sv, off, 64);
  }
  if (lane == 0) {
    const float inv = sv > 0.f ? 1.0f / sv : 1.0f;
    out[0] = 20.0f * pf * inv;
    out[1] = pd * inv;
    out[2] = pi * inv;
  }
}

extern "C" void kernel_launch(void* const* d_in, const int* in_sizes, int n_in,
                              void* d_out, int out_size, void* d_ws,
                              size_t ws_size, hipStream_t stream) {
  const float* pred_masks = (const float*)d_in[0];
  const float* pred_ious = (const float*)d_in[1];
  const float* targets = (const float*)d_in[2];
  float* out = (float*)d_out;
  float* ws = (float*)d_ws;

  hipMemsetAsync(ws, 0, WS_FLOATS * sizeof(float), stream);
  sam_loss_pass1<<<NB * NK * CPB, TPB, 0, stream>>>(pred_masks, targets, ws);
  sam_loss_pass2<<<1, 64, 0, stream>>>(ws, pred_ious, out);
}

// Round 6
// 221.748 us; speedup vs baseline: 1.0416x; 1.0416x over previous
//
#include <hip/hip_runtime.h>

#define NPIX (512 * 512)  // 262144
#define NB 32
#define NK 4
#define TPB 256
#define CPB 64                      // chunks per (b,k)
#define CHUNK (NPIX / CPB)          // 4096 elems
#define T4PT (CHUNK / (TPB * 4))    // 4 float4 per thread per input

// ws layout (floats):
// [0..127]   focal_sum  (b*4+k)
// [128..255] p_sum
// [256..383] inter
// [384..511] m_sum
// [512..639] mi
// [640..671] t_sum (per b)
#define TSUM_OFF (5 * NB * NK)
#define WS_FLOATS 672

__device__ __forceinline__ float area_lo(int k) {
  return k == 0 ? 0.04f : (k == 1 ? 0.0f : (k == 2 ? 0.01f : 0.16f));
}
__device__ __forceinline__ float area_hi(int k) {
  return k == 0 ? 0.64f : (k == 1 ? 0.04f : (k == 2 ? 0.25f : 1.0f));
}

// ---- t_sum pre-scan: 32 MB, exact integer sums ----
__global__ __launch_bounds__(TPB, 8) void sam_loss_tsum(
    const float* __restrict__ t, float* __restrict__ ws) {
  const int blk = blockIdx.x;  // b*CPB + c
  const int b = blk >> 6;
  const int c = blk & (CPB - 1);
  const float4* __restrict__ t4 =
      (const float4*)(t + (size_t)b * NPIX + (size_t)c * CHUNK);
  float ts = 0.f;
#pragma unroll
  for (int it = 0; it < T4PT; ++it) {
    const float4 tv = t4[it * TPB + threadIdx.x];
    ts += (tv.x + tv.y) + (tv.z + tv.w);
  }
#pragma unroll
  for (int off = 32; off > 0; off >>= 1) ts += __shfl_down(ts, off, 64);
  __shared__ float red[TPB / 64];
  const int lane = threadIdx.x & 63;
  const int wid = threadIdx.x >> 6;
  if (lane == 0) red[wid] = ts;
  __syncthreads();
  if (threadIdx.x == 0) {
    atomicAdd(ws + TSUM_OFF + b, red[0] + red[1] + red[2] + red[3]);
  }
}

// ---- main pass: early-exits invalid (b,k) before any bulk loads ----
__global__ __launch_bounds__(TPB, 8) void sam_loss_pass1(
    const float* __restrict__ x, const float* __restrict__ t,
    float* __restrict__ ws) {
  // XCD-aware swizzle: 4 k-siblings of one (b,c) chunk differ by 8 in
  // blockIdx -> same XCD -> t-chunk reused from that L2.
  const int blk = blockIdx.x;            // (bc>>3)*32 + k*8 + (bc&7)
  const int low = blk & 7;
  const int k = (blk >> 3) & 3;
  const int bc = ((blk >> 5) << 3) | low;
  const int b = bc >> 6;                 // bc / CPB
  const int c = bc & (CPB - 1);          // bc % CPB

  // validity gate (uniform per block): skip all work for masked (b,k)
  const float tsum = ws[TSUM_OFF + b];
  const float ratio = tsum * (1.0f / (float)NPIX);
  if (!(ratio > area_lo(k) && ratio < area_hi(k))) return;

  const float4* __restrict__ t4 =
      (const float4*)(t + (size_t)b * NPIX + (size_t)c * CHUNK);
  const float4* __restrict__ x4 =
      (const float4*)(x + ((size_t)b * NK + k) * NPIX + (size_t)c * CHUNK);

  // issue all 8 loads up front (8 KB/wave in flight)
  float4 xv[T4PT], tv[T4PT];
#pragma unroll
  for (int it = 0; it < T4PT; ++it) {
    const int i = it * TPB + threadIdx.x;
    xv[it] = x4[i];
    tv[it] = t4[i];
  }

  float fs = 0.f, ps = 0.f, is_ = 0.f, ms = 0.f, mi = 0.f;
#pragma unroll
  for (int it = 0; it < T4PT; ++it) {
    const float xx[4] = {xv[it].x, xv[it].y, xv[it].z, xv[it].w};
    const float tt[4] = {tv[it].x, tv[it].y, tv[it].z, tv[it].w};
#pragma unroll
    for (int j = 0; j < 4; ++j) {
      const float xf = xx[j];
      const float tf = tt[j];                            // exactly 0.0 or 1.0
      const float ax = fabsf(xf);
      const float e = __expf(-ax);                       // exp(-|x|) in (0,1]
      const float denom = 1.0f + e;
      const float r = __builtin_amdgcn_rcpf(denom);      // sigmoid(|x|)
      const float l1 = __logf(denom);                    // log1p(e)
      const float er = e * r;                            // sigmoid(-|x|)
      const bool pos = xf >= 0.0f;
      const bool tpos = tf != 0.0f;
      const bool mx = pos != tpos;
      const float bce = (mx ? ax : 0.0f) + l1;           // t?sp(-x):sp(x)
      const float om = mx ? r : er;                      // 1 - exp(-bce)
      fs = fmaf(om * om, bce, fs);
      const float sp = pos ? r : er;                     // sigmoid(x)
      ps += sp;
      is_ = fmaf(sp, tf, is_);
      const float mf = pos ? 1.0f : 0.0f;
      ms += mf;
      mi = fmaf(mf, tf, mi);
    }
  }

  // thread -> wave -> block -> global reduction of 5 values
  __shared__ float red[TPB / 64][5];
  const int lane = threadIdx.x & 63;
  const int wid = threadIdx.x >> 6;
  float vals[5] = {fs, ps, is_, ms, mi};
#pragma unroll
  for (int j = 0; j < 5; ++j) {
    float v = vals[j];
#pragma unroll
    for (int off = 32; off > 0; off >>= 1) v += __shfl_down(v, off, 64);
    if (lane == 0) red[wid][j] = v;
  }
  __syncthreads();
  if (threadIdx.x < 5) {
    const int j = threadIdx.x;
    const float v = red[0][j] + red[1][j] + red[2][j] + red[3][j];
    atomicAdd(ws + j * (NB * NK) + b * NK + k, v);
  }
}

__global__ __launch_bounds__(64) void sam_loss_pass2(
    const float* __restrict__ ws, const float* __restrict__ ious,
    float* __restrict__ out) {
  const float S = 1e-4f;
  const int lane = threadIdx.x;

  float pf = 0.f, pd = 0.f, pi = 0.f, sv = 0.f;
  if (lane < NB) {
    const int b = lane;
    const float tsum = ws[TSUM_OFF + b];
    const float ratio = tsum * (1.0f / (float)NPIX);
    float cnt = 0.f, sf = 0.f, sd = 0.f, si = 0.f;
#pragma unroll
    for (int k = 0; k < NK; ++k) {
      const bool valid = (ratio > area_lo(k)) && (ratio < area_hi(k));
      if (valid) {
        const int idx = b * NK + k;
        const float focal = 0.8f * ws[idx] / (float)NPIX;
        const float psum = ws[1 * (NB * NK) + idx];
        const float inter = ws[2 * (NB * NK) + idx];
        const float msum = ws[3 * (NB * NK) + idx];
        const float mi = ws[4 * (NB * NK) + idx];
        const float dice = 1.0f - (2.0f * inter + S) / (psum + tsum + S);
        const float iou_gt = (mi + S) / (msum + tsum - mi + S);
        const float d = ious[idx] - iou_gt;
        cnt += 1.0f;
        sf += focal;
        sd += dice;
        si += d * d;
      }
    }
    if (cnt > 0.f) {
      pf = sf / cnt;
      pd = sd / cnt;
      pi = si / cnt;
      sv = 1.0f;
    }
  }
#pragma unroll
  for (int off = 32; off > 0; off >>= 1) {
    pf += __shfl_down(pf, off, 64);
    pd += __shfl_down(pd, off, 64);
    pi += __shfl_down(pi, off, 64);
    sv += __shfl_down(sv, off, 64);
  }
  if (lane == 0) {
    const float inv = sv > 0.f ? 1.0f / sv : 1.0f;
    out[0] = 20.0f * pf * inv;
    out[1] = pd * inv;
    out[2] = pi * inv;
  }
}

extern "C" void kernel_launch(void* const* d_in, const int* in_sizes, int n_in,
                              void* d_out, int out_size, void* d_ws,
                              size_t ws_size, hipStream_t stream) {
  const float* pred_masks = (const float*)d_in[0];
  const float* pred_ious = (const float*)d_in[1];
  const float* targets = (const float*)d_in[2];
  float* out = (float*)d_out;
  float* ws = (float*)d_ws;

  hipMemsetAsync(ws, 0, WS_FLOATS * sizeof(float), stream);
  sam_loss_tsum<<<NB * CPB, TPB, 0, stream>>>(targets, ws);
  sam_loss_pass1<<<NB * NK * CPB, TPB, 0, stream>>>(pred_masks, targets, ws);
  sam_loss_pass2<<<1, 64, 0, stream>>>(ws, pred_ious, out);
}